// Round 4
// baseline (683.987 us; speedup 1.0000x reference)
//
#include <hip/hip_runtime.h>
#include <math.h>

#define DIM_ 2048
#define HID_ 8192
#define SEQ_ 2048
#define BATCH_ 2
#define TOK_ (BATCH_*SEQ_)

typedef __attribute__((ext_vector_type(4))) float f32x4;
typedef __attribute__((ext_vector_type(8))) __bf16 bf16x8;
typedef __attribute__((ext_vector_type(4))) unsigned int u32x4;
typedef __attribute__((ext_vector_type(4))) short s16x4;
typedef __attribute__((address_space(3))) short* lds_sp;

__device__ __forceinline__ short f2bf(float f) {
  union { float f; unsigned u; } v; v.f = f;
  unsigned r = v.u + 0x7FFFu + ((v.u >> 16) & 1u);
  return (short)(r >> 16);
}

__device__ __forceinline__ f32x4 mfma16(u32x4 a, u32x4 b, f32x4 c) {
  return __builtin_amdgcn_mfma_f32_16x16x32_bf16(
      __builtin_bit_cast(bf16x8, a), __builtin_bit_cast(bf16x8, b), c, 0, 0, 0);
}

#define DSR(dst, addr) asm volatile("ds_read_b128 %0, %1" : "=v"(dst) : "v"(addr))
#define BARv()  __builtin_amdgcn_s_barrier()
#define LGKM0() do { asm volatile("s_waitcnt lgkmcnt(0)" ::: "memory"); \
                     __builtin_amdgcn_sched_barrier(0); } while(0)
#define LGKM8() asm volatile("s_waitcnt lgkmcnt(8)" ::: "memory")
#define VM6()   asm volatile("s_waitcnt vmcnt(6)" ::: "memory")
#define VM4()   asm volatile("s_waitcnt vmcnt(4)" ::: "memory")
#define PRIO1() __builtin_amdgcn_s_setprio(1)
#define PRIO0() __builtin_amdgcn_s_setprio(0)

// XCD-chunk + 4-column-group tile mapping (bijective; needs nwg%8==0, gx%4==0)
#define TILE_MAP(BM, BN) \
  const int nwg  = gridDim.x * gridDim.y; \
  const int orig = blockIdx.y * gridDim.x + blockIdx.x; \
  const int wgid = (orig & 7) * (nwg >> 3) + (orig >> 3); \
  const int gy4  = (int)gridDim.y << 2; \
  const int rem  = wgid % gy4; \
  const int tn   = ((wgid / gy4) * 4 + (rem & 3)) * (BN); \
  const int tm   = (rem >> 2) * (BM);

// ---------------------------------------------------------------------------
// gemm256: 256x256 tile, BK=64, 8 waves (2M x 4N), per-wave 128x64 output.
// m201-style 8 phases / 2 K-tiles, half-tile staggered staging:
//   P1/P2: stage A(t+1)->buf1 | P3/P4: B(t+2)->buf0 | P5/P6: A(t+2)->buf0
//   P7/P8: B(t+3)->buf1 ; vmcnt(4) only at P4 and P8 (4 loads in flight).
// WAR: each region staged only after its reads drained >=1 barrier earlier.
// LDS 128KB: As[2buf][2half][128][64], Bs same. T2 slot-XOR swizzle.
// C[M,N] = A[M,K](bf16,lda) @ B^T, B stored N x K (bf16,ldb).
// ---------------------------------------------------------------------------
#define RA(mh, bufofs) do { \
  _Pragma("unroll") \
  for (int f_ = 0; f_ < 4; ++f_) { \
    DSR(af[f_][0], aBase + (bufofs) + ((mh)*4+f_)*2048u + offk0); \
    DSR(af[f_][1], aBase + (bufofs) + ((mh)*4+f_)*2048u + offk1); \
  } \
} while(0)

#define RB(nh, bufofs) do { \
  DSR(bq[nh][0][0], bBase + (bufofs) + (nh)*4096u + offk0); \
  DSR(bq[nh][0][1], bBase + (bufofs) + (nh)*4096u + offk1); \
  DSR(bq[nh][1][0], bBase + (bufofs) + (nh)*4096u + 2048u + offk0); \
  DSR(bq[nh][1][1], bBase + (bufofs) + (nh)*4096u + 2048u + offk1); \
} while(0)

#define MMQ(mh, nh) do { \
  _Pragma("unroll") \
  for (int f_ = 0; f_ < 4; ++f_) { \
    _Pragma("unroll") \
    for (int c_ = 0; c_ < 2; ++c_) { \
      acc[(mh)*4+f_][(nh)*2+c_] = mfma16(af[f_][0], bq[nh][c_][0], acc[(mh)*4+f_][(nh)*2+c_]); \
      acc[(mh)*4+f_][(nh)*2+c_] = mfma16(af[f_][1], bq[nh][c_][1], acc[(mh)*4+f_][(nh)*2+c_]); \
    } \
  } \
} while(0)

template<int EPI>
__global__ __launch_bounds__(512, 2)
void gemm256(const short* __restrict__ A, const short* __restrict__ B,
             void* __restrict__ Cv, const float* __restrict__ bias,
             const float* __restrict__ aux,
             int M, int N, int K, int lda, int ldb, int ldc,
             long long sA, long long sB, long long sC)
{
  __shared__ __align__(16) short As[4*128*64];   // 64 KB: [buf][half][128][64]
  __shared__ __align__(16) short Bs[4*128*64];   // 64 KB
  const int lane = threadIdx.x & 63;
  const int wave = threadIdx.x >> 6;
  const int wr = wave >> 2, wc = wave & 3;       // 2M x 4N waves
  TILE_MAP(256, 256)
  const int z = blockIdx.z;
  A += (long long)z * sA;
  B += (long long)z * sB;

  const int NT = K >> 6;          // K-tiles (even for all our shapes)
  const int NI = NT >> 1;

  // staging geometry (linear LDS dest, pre-swizzled source; rule #21)
  const int lr    = lane >> 3;
  const int lrow8 = wave * 8 + lr;
  const int swz   = ((lane & 7) ^ lr) << 3;
  const short* pA0 = A + (long long)(tm + lrow8) * lda + swz;
  const short* pA1 = pA0 + 128LL * lda;
  const short* pB0 = B + (long long)(tn + lrow8) * ldb + swz;
  const short* pB1 = pB0 + 128LL * ldb;

  auto stA = [&](const short* p, int t, int reg) {
    const short* s = p + ((long long)t << 6);
    __builtin_amdgcn_global_load_lds(
        (const __attribute__((address_space(1))) void*)s,
        (__attribute__((address_space(3))) void*)(As + reg + wave * 512), 16, 0, 0);
    __builtin_amdgcn_global_load_lds(
        (const __attribute__((address_space(1))) void*)(s + ((long long)lda << 6)),
        (__attribute__((address_space(3))) void*)(As + reg + 4096 + wave * 512), 16, 0, 0);
  };
  auto stB = [&](const short* p, int t, int reg) {
    const short* s = p + ((long long)t << 6);
    __builtin_amdgcn_global_load_lds(
        (const __attribute__((address_space(1))) void*)s,
        (__attribute__((address_space(3))) void*)(Bs + reg + wave * 512), 16, 0, 0);
    __builtin_amdgcn_global_load_lds(
        (const __attribute__((address_space(1))) void*)(s + ((long long)ldb << 6)),
        (__attribute__((address_space(3))) void*)(Bs + reg + 4096 + wave * 512), 16, 0, 0);
  };

  // LDS read addressing (phys k-slot = logical ^ (row&7))
  const unsigned asB = (unsigned)(unsigned long long)(lds_sp)As;
  const unsigned bsB = (unsigned)(unsigned long long)(lds_sp)Bs;
  const int l15 = lane & 15, l4 = lane >> 4;
  const unsigned offk0 = (unsigned)(( l4      ^ (lane & 7)) << 4);
  const unsigned offk1 = (unsigned)(((l4 + 4) ^ (lane & 7)) << 4);
  const unsigned aBase = asB + (unsigned)(wr * 16384 + l15 * 128);
  const unsigned bBase = bsB + (unsigned)((wc >> 1) * 16384 + (wc & 1) * 8192 + l15 * 128);

  f32x4 acc[8][4] = {};
  u32x4 af[4][2], bq[2][2][2];

  // prologue: A(0),B(0)->buf0, B(1)->buf1 (12 loads); vmcnt(4) leaves B(1)
  stA(pA0, 0, 0);     stA(pA1, 0, 8192);
  stB(pB0, 0, 0);     stB(pB1, 0, 8192);
  stB(pB0, 1, 16384); stB(pB1, 1, 24576);
  VM4(); BARv();

  #pragma unroll 1
  for (int i = 0; i < NI; ++i) {
    const int t   = 2 * i;
    const int tA  = t + 1;
    const int t2  = t + 2 < NT ? t + 2 : NT - 1;
    const int t3  = t + 3 < NT ? t + 3 : NT - 1;
    // ---- tile t (buf0) ----
    RA(0, 0u); RB(0, 0u);
    stA(pA0, tA, 16384);
    LGKM8(); BARv(); LGKM0();
    PRIO1(); MMQ(0, 0); PRIO0(); BARv();

    RB(1, 0u);
    stA(pA1, tA, 24576);
    BARv(); LGKM0();
    PRIO1(); MMQ(0, 1); PRIO0(); BARv();

    RA(1, 0u);
    stB(pB0, t2, 0);
    BARv(); LGKM0();
    PRIO1(); MMQ(1, 0); PRIO0(); BARv();

    stB(pB1, t2, 8192);
    VM4(); BARv();
    PRIO1(); MMQ(1, 1); PRIO0(); BARv();
    // ---- tile t+1 (buf1) ----
    RA(0, 32768u); RB(0, 32768u);
    stA(pA0, t2, 0);
    LGKM8(); BARv(); LGKM0();
    PRIO1(); MMQ(0, 0); PRIO0(); BARv();

    RB(1, 32768u);
    stA(pA1, t2, 8192);
    BARv(); LGKM0();
    PRIO1(); MMQ(0, 1); PRIO0(); BARv();

    RA(1, 32768u);
    stB(pB0, t3, 16384);
    BARv(); LGKM0();
    PRIO1(); MMQ(1, 0); PRIO0(); BARv();

    stB(pB1, t3, 24576);
    VM4(); BARv();
    PRIO1(); MMQ(1, 1); PRIO0(); BARv();
  }

  // epilogue: row = tm + wr*128 + fr*16 + l4*4 + j ; col = tn + wc*64 + fc*16 + l15
  const int row0 = tm + wr * 128 + l4 * 4;
  const int col0 = tn + wc * 64 + l15;
  #pragma unroll
  for (int fr = 0; fr < 8; ++fr) {
    #pragma unroll
    for (int j = 0; j < 4; ++j) {
      const int row = row0 + fr * 16 + j;
      #pragma unroll
      for (int fc = 0; fc < 4; ++fc) {
        const int col = col0 + fc * 16;
        float v = acc[fr][fc][j];
        if (EPI == 1) {
          ((float*)Cv + (long long)z * sC)[(long long)row * ldc + col] = v;
        } else if (EPI == 0) {
          v += bias[col];
          ((short*)Cv + (long long)z * sC)[(long long)row * ldc + col] = f2bf(v);
        } else if (EPI == 2) {
          v += bias[col];
          v = 0.5f * v * (1.0f + erff(v * 0.70710678118654752f));
          ((short*)Cv + (long long)z * sC)[(long long)row * ldc + col] = f2bf(v);
        } else {
          v += bias[col] + aux[(long long)row * ldc + col];
          ((float*)Cv + (long long)z * sC)[(long long)row * ldc + col] = v;
        }
      }
    }
  }
}

// ---------------------------------------------------------------------------
// gemm8p: 128x256 tile, BK=64, 3-slot rotation (round-3 verified) — used for
// the small-grid GEMMs (QK^T, PV, FFN2) where 256^2 would underfill the chip.
// ---------------------------------------------------------------------------
#define RD_A(mlo, slot) do { \
  const unsigned ab_ = aBase8 + (unsigned)(slot)*16384u + (mlo)*2048u; \
  DSR(af[0][0], ab_ + offk0);         DSR(af[0][1], ab_ + offk1); \
  DSR(af[1][0], ab_ + 2048u + offk0); DSR(af[1][1], ab_ + 2048u + offk1); \
} while(0)

#define RD_B(slot) do { \
  const unsigned bb_ = bBase8 + (unsigned)(slot)*32768u; \
  DSR(bfr[0][0], bb_ + offk0);         DSR(bfr[0][1], bb_ + offk1); \
  DSR(bfr[1][0], bb_ + 2048u + offk0); DSR(bfr[1][1], bb_ + 2048u + offk1); \
  DSR(bfr[2][0], bb_ + 4096u + offk0); DSR(bfr[2][1], bb_ + 4096u + offk1); \
  DSR(bfr[3][0], bb_ + 6144u + offk0); DSR(bfr[3][1], bb_ + 6144u + offk1); \
} while(0)

#define MM(mlo) do { \
  _Pragma("unroll") \
  for (int n_ = 0; n_ < 4; ++n_) { \
    acc[(mlo)][n_]   = mfma16(af[0][0], bfr[n_][0], acc[(mlo)][n_]); \
    acc[(mlo)][n_]   = mfma16(af[0][1], bfr[n_][1], acc[(mlo)][n_]); \
    acc[(mlo)+1][n_] = mfma16(af[1][0], bfr[n_][0], acc[(mlo)+1][n_]); \
    acc[(mlo)+1][n_] = mfma16(af[1][1], bfr[n_][1], acc[(mlo)+1][n_]); \
  } \
} while(0)

template<int EPI>
__global__ __launch_bounds__(512, 2)
void gemm8p(const short* __restrict__ A, const short* __restrict__ B,
            void* __restrict__ Cv, const float* __restrict__ bias,
            const float* __restrict__ aux,
            int M, int N, int K, int lda, int ldb, int ldc,
            long long sA, long long sB, long long sC)
{
  __shared__ __align__(16) short As[3*128*64];   // 48 KB (3 slots)
  __shared__ __align__(16) short Bs[3*256*64];   // 96 KB (3 slots)
  const int lane = threadIdx.x & 63;
  const int wave = threadIdx.x >> 6;
  const int wr = wave >> 2, wc = wave & 3;       // 2 x 4 waves
  TILE_MAP(128, 256)
  const int z  = blockIdx.z;
  A += (long long)z * sA;
  B += (long long)z * sB;

  const int NT = K >> 6;          // 64-wide K tiles

  const int lr    = lane >> 3;
  const int lrow  = wave * 8 + lr;
  const int lslot = ((lane & 7) ^ lr) << 3;
  const short* pA = A + (long long)(tm + lrow) * lda + lslot;
  const short* pB = B + (long long)(tn + lrow) * ldb + lslot;
  const long long lda64 = 64LL * lda;
  const long long ldb64 = 64LL * ldb;

  auto stageA = [&](int t, int slot) {
    const long long ko = (long long)t << 6;
    const int db = slot * 8192 + wave * 512;
    __builtin_amdgcn_global_load_lds(
        (const __attribute__((address_space(1))) void*)(pA + ko),
        (__attribute__((address_space(3))) void*)(As + db), 16, 0, 0);
    __builtin_amdgcn_global_load_lds(
        (const __attribute__((address_space(1))) void*)(pA + lda64 + ko),
        (__attribute__((address_space(3))) void*)(As + db + 4096), 16, 0, 0);
  };
  auto stageB = [&](int t, int slot) {
    const long long ko = (long long)t << 6;
    const int db = slot * 16384 + wave * 512;
    __builtin_amdgcn_global_load_lds(
        (const __attribute__((address_space(1))) void*)(pB + ko),
        (__attribute__((address_space(3))) void*)(Bs + db), 16, 0, 0);
    __builtin_amdgcn_global_load_lds(
        (const __attribute__((address_space(1))) void*)(pB + ldb64 + ko),
        (__attribute__((address_space(3))) void*)(Bs + db + 4096), 16, 0, 0);
    __builtin_amdgcn_global_load_lds(
        (const __attribute__((address_space(1))) void*)(pB + 2*ldb64 + ko),
        (__attribute__((address_space(3))) void*)(Bs + db + 8192), 16, 0, 0);
    __builtin_amdgcn_global_load_lds(
        (const __attribute__((address_space(1))) void*)(pB + 3*ldb64 + ko),
        (__attribute__((address_space(3))) void*)(Bs + db + 12288), 16, 0, 0);
  };

  const unsigned asB = (unsigned)(unsigned long long)(lds_sp)As;
  const unsigned bsB = (unsigned)(unsigned long long)(lds_sp)Bs;
  const int l15 = lane & 15, l4 = lane >> 4;
  const unsigned offk0 = (unsigned)(( l4      ^ (lane & 7)) << 4);
  const unsigned offk1 = (unsigned)(((l4 + 4) ^ (lane & 7)) << 4);
  const unsigned aBase8 = asB + (unsigned)((wr * 64 + l15) * 128);
  const unsigned bBase8 = bsB + (unsigned)((wc * 64 + l15) * 128);

  f32x4 acc[4][4] = {};
  u32x4 af[2][2], bfr[4][2];

  stageB(0, 0); stageA(0, 0);
  stageB(1 < NT ? 1 : 0, 1); stageA(1 < NT ? 1 : 0, 1);
  VM6();
  BARv();

  int rd = 0;
  #pragma unroll 1
  for (int t = 0; t < NT; ++t) {
    const int st = rd + 2 >= 3 ? rd - 1 : rd + 2;          // (t+2) % 3
    const int tc = t + 2 < NT ? t + 2 : NT - 1;
    RD_A(0, rd); RD_B(rd);
    stageB(tc, st);
    LGKM8();
    BARv(); LGKM0();
    PRIO1(); MM(0); PRIO0();
    BARv();
    RD_A(2, rd);
    stageA(tc, st);
    VM6();
    BARv(); LGKM0();
    PRIO1(); MM(2); PRIO0();
    BARv();
    rd = rd + 1 >= 3 ? 0 : rd + 1;
  }

  const int row0 = tm + wr * 64 + l4 * 4;
  const int col0 = tn + wc * 64 + l15;
  #pragma unroll
  for (int mi = 0; mi < 4; ++mi) {
    #pragma unroll
    for (int j = 0; j < 4; ++j) {
      const int row = row0 + mi * 16 + j;
      #pragma unroll
      for (int ni = 0; ni < 4; ++ni) {
        const int col = col0 + ni * 16;
        float v = acc[mi][ni][j];
        if (EPI == 1) {
          ((float*)Cv + (long long)z * sC)[(long long)row * ldc + col] = v;
        } else if (EPI == 0) {
          v += bias[col];
          ((short*)Cv + (long long)z * sC)[(long long)row * ldc + col] = f2bf(v);
        } else if (EPI == 2) {
          v += bias[col];
          v = 0.5f * v * (1.0f + erff(v * 0.70710678118654752f));
          ((short*)Cv + (long long)z * sC)[(long long)row * ldc + col] = f2bf(v);
        } else {
          v += bias[col] + aux[(long long)row * ldc + col];
          ((float*)Cv + (long long)z * sC)[(long long)row * ldc + col] = v;
        }
      }
    }
  }
}

// ---------------------------------------------------------------------------
// LayerNorm: out_bf16[row] = LN(x[row] (+ res[row])) * g + b   (row = 2048 f32)
// ---------------------------------------------------------------------------
__global__ __launch_bounds__(256)
void ln_kernel(const float* __restrict__ x, const float* __restrict__ res,
               const float* __restrict__ g, const float* __restrict__ b,
               short* __restrict__ out, int hasres)
{
  const int row = blockIdx.x;
  const int tid = threadIdx.x;
  const float4* X = (const float4*)x + (long long)row * 512;
  float4 v0 = X[tid], v1 = X[tid + 256];
  if (hasres) {
    const float4* R = (const float4*)res + (long long)row * 512;
    float4 r0 = R[tid], r1 = R[tid + 256];
    v0.x += r0.x; v0.y += r0.y; v0.z += r0.z; v0.w += r0.w;
    v1.x += r1.x; v1.y += r1.y; v1.z += r1.z; v1.w += r1.w;
  }
  float s1 = v0.x + v0.y + v0.z + v0.w + v1.x + v1.y + v1.z + v1.w;
  float s2 = v0.x*v0.x + v0.y*v0.y + v0.z*v0.z + v0.w*v0.w
           + v1.x*v1.x + v1.y*v1.y + v1.z*v1.z + v1.w*v1.w;
  #pragma unroll
  for (int o = 32; o > 0; o >>= 1) { s1 += __shfl_xor(s1, o); s2 += __shfl_xor(s2, o); }
  __shared__ float red[8];
  if ((tid & 63) == 0) { red[tid >> 6] = s1; red[4 + (tid >> 6)] = s2; }
  __syncthreads();
  s1 = red[0] + red[1] + red[2] + red[3];
  s2 = red[4] + red[5] + red[6] + red[7];
  const float mean = s1 * (1.0f / 2048.0f);
  const float var  = s2 * (1.0f / 2048.0f) - mean * mean;
  const float rstd = rsqrtf(var + 1e-5f);
  const float4* G  = (const float4*)g;
  const float4* Bb = (const float4*)b;
  float4 g0 = G[tid], g1 = G[tid + 256], b0 = Bb[tid], b1 = Bb[tid + 256];
  s16x4 o0, o1;
  o0[0] = f2bf((v0.x - mean) * rstd * g0.x + b0.x);
  o0[1] = f2bf((v0.y - mean) * rstd * g0.y + b0.y);
  o0[2] = f2bf((v0.z - mean) * rstd * g0.z + b0.z);
  o0[3] = f2bf((v0.w - mean) * rstd * g0.w + b0.w);
  o1[0] = f2bf((v1.x - mean) * rstd * g1.x + b1.x);
  o1[1] = f2bf((v1.y - mean) * rstd * g1.y + b1.y);
  o1[2] = f2bf((v1.z - mean) * rstd * g1.z + b1.z);
  o1[3] = f2bf((v1.w - mean) * rstd * g1.w + b1.w);
  *(s16x4*)&out[(long long)row * 2048 + tid * 4]        = o0;
  *(s16x4*)&out[(long long)row * 2048 + 1024 + tid * 4] = o1;
}

// ---------------------------------------------------------------------------
// Softmax: probs_bf16 = softmax(scores*scale + mask[q])
// ---------------------------------------------------------------------------
__global__ __launch_bounds__(256)
void softmax_kernel(const float* __restrict__ scores, const float* __restrict__ mask,
                    short* __restrict__ probs)
{
  const long long row = blockIdx.x;          // b*SEQ + q
  const int q  = blockIdx.x & (SEQ_ - 1);
  const int tid = threadIdx.x;
  const float scale = 0.022097086912079608f; // 1/sqrt(2048)
  const float4* S  = (const float4*)scores + row * 512;
  const float4* Mk = (const float4*)mask + (long long)q * 512;
  float4 v0 = S[tid], v1 = S[tid + 256];
  float4 m0 = Mk[tid], m1 = Mk[tid + 256];
  float a[8] = { v0.x*scale + m0.x, v0.y*scale + m0.y, v0.z*scale + m0.z, v0.w*scale + m0.w,
                 v1.x*scale + m1.x, v1.y*scale + m1.y, v1.z*scale + m1.z, v1.w*scale + m1.w };
  float mx = a[0];
  #pragma unroll
  for (int i = 1; i < 8; ++i) mx = fmaxf(mx, a[i]);
  #pragma unroll
  for (int o = 32; o > 0; o >>= 1) mx = fmaxf(mx, __shfl_xor(mx, o));
  __shared__ float red[8];
  if ((tid & 63) == 0) red[tid >> 6] = mx;
  __syncthreads();
  mx = fmaxf(fmaxf(red[0], red[1]), fmaxf(red[2], red[3]));
  float e[8], sum = 0.f;
  #pragma unroll
  for (int i = 0; i < 8; ++i) { e[i] = __expf(a[i] - mx); sum += e[i]; }
  #pragma unroll
  for (int o = 32; o > 0; o >>= 1) sum += __shfl_xor(sum, o);
  if ((tid & 63) == 0) red[4 + (tid >> 6)] = sum;
  __syncthreads();
  sum = red[4] + red[5] + red[6] + red[7];
  const float inv = 1.0f / sum;
  s16x4 o0, o1;
  #pragma unroll
  for (int i = 0; i < 4; ++i) o0[i] = f2bf(e[i] * inv);
  #pragma unroll
  for (int i = 0; i < 4; ++i) o1[i] = f2bf(e[4 + i] * inv);
  probs += row * 2048;
  *(s16x4*)&probs[tid * 4]        = o0;
  *(s16x4*)&probs[1024 + tid * 4] = o1;
}

// ---------------------------------------------------------------------------
// fp32 (R,C) -> bf16 (C,R) transpose-convert (weights)
// ---------------------------------------------------------------------------
__global__ __launch_bounds__(256)
void cvt_transpose_kernel(const float* __restrict__ in, short* __restrict__ out,
                          int R, int C)
{
  __shared__ float t[32][33];
  const int tx = threadIdx.x & 31, ty = threadIdx.x >> 5;
  const int r0 = blockIdx.y << 5, c0 = blockIdx.x << 5;
  #pragma unroll
  for (int i = 0; i < 32; i += 8)
    t[ty + i][tx] = in[(long long)(r0 + ty + i) * C + c0 + tx];
  __syncthreads();
  #pragma unroll
  for (int i = 0; i < 32; i += 8)
    out[(long long)(c0 + ty + i) * R + r0 + tx] = f2bf(t[tx][ty + i]);
}

// bf16 strided (z,R,C) -> (z,C,R) transpose (V)
__global__ __launch_bounds__(256)
void transpose_bf16_kernel(const short* __restrict__ in, short* __restrict__ out,
                           int ldin, int ldout, long long sin_, long long sout_)
{
  __shared__ short t[32][33];
  in  += (long long)blockIdx.z * sin_;
  out += (long long)blockIdx.z * sout_;
  const int tx = threadIdx.x & 31, ty = threadIdx.x >> 5;
  const int r0 = blockIdx.y << 5, c0 = blockIdx.x << 5;
  #pragma unroll
  for (int i = 0; i < 32; i += 8)
    t[ty + i][tx] = in[(long long)(r0 + ty + i) * ldin + c0 + tx];
  __syncthreads();
  #pragma unroll
  for (int i = 0; i < 32; i += 8)
    out[(long long)(c0 + ty + i) * ldout + r0 + tx] = t[tx][ty + i];
}

__global__ __launch_bounds__(256)
void concat_bias_kernel(const float* a, const float* b, const float* c, float* o)
{
  const int i = blockIdx.x * 256 + threadIdx.x;   // 6144
  o[i] = i < 2048 ? a[i] : (i < 4096 ? b[i - 2048] : c[i - 4096]);
}

// ---------------------------------------------------------------------------
extern "C" void kernel_launch(void* const* d_in, const int* in_sizes, int n_in,
                              void* d_out, int out_size, void* d_ws, size_t ws_size,
                              hipStream_t stream)
{
  const float* x    = (const float*)d_in[0];
  const float* mask = (const float*)d_in[1];
  const float* wq   = (const float*)d_in[4];
  const float* bq   = (const float*)d_in[5];
  const float* wk   = (const float*)d_in[6];
  const float* bk   = (const float*)d_in[7];
  const float* wv   = (const float*)d_in[8];
  const float* bv   = (const float*)d_in[9];
  const float* g1   = (const float*)d_in[10];
  const float* b1   = (const float*)d_in[11];
  const float* g2   = (const float*)d_in[12];
  const float* b2   = (const float*)d_in[13];
  const float* w1   = (const float*)d_in[14];
  const float* bw1  = (const float*)d_in[15];
  const float* w2   = (const float*)d_in[16];
  const float* bw2  = (const float*)d_in[17];
  float* out = (float*)d_out;

  char* p = (char*)d_ws;
  auto take = [&](size_t bytes) { char* r = p; p += (bytes + 255) & ~(size_t)255; return r; };
  short* wqkvT = (short*)take((size_t)3 * DIM_ * DIM_ * 2);  // [6144][2048] bf16
  short* w1T   = (short*)take((size_t)DIM_ * HID_ * 2);      // [8192][2048]
  short* w2T   = (short*)take((size_t)HID_ * DIM_ * 2);      // [2048][8192]
  short* h_bf  = (short*)take((size_t)TOK_ * DIM_ * 2);      // reused as h2
  short* qkv   = (short*)take((size_t)TOK_ * 3 * DIM_ * 2);  // [4096][6144]
  short* vT    = (short*)take((size_t)BATCH_ * DIM_ * SEQ_ * 2);
  float* scores= (float*)take((size_t)BATCH_ * SEQ_ * SEQ_ * 4); // reused as attn_out
  short* attn  = (short*)take((size_t)BATCH_ * SEQ_ * SEQ_ * 2);
  float* cbias = (float*)take((size_t)3 * DIM_ * 4);
  short* ffn1  = qkv;          // 64MB alias over qkv+vT (dead after PV)
  float* attno = scores;       // alias (scores dead after softmax)
  short* h2    = h_bf;         // alias (h dead after QKV)

  const dim3 blk(256), gblk(512);
  // weight convert+transpose
  cvt_transpose_kernel<<<dim3(DIM_/32, DIM_/32), blk, 0, stream>>>(wq, wqkvT, DIM_, DIM_);
  cvt_transpose_kernel<<<dim3(DIM_/32, DIM_/32), blk, 0, stream>>>(wk, wqkvT + (size_t)DIM_*DIM_, DIM_, DIM_);
  cvt_transpose_kernel<<<dim3(DIM_/32, DIM_/32), blk, 0, stream>>>(wv, wqkvT + (size_t)2*DIM_*DIM_, DIM_, DIM_);
  cvt_transpose_kernel<<<dim3(HID_/32, DIM_/32), blk, 0, stream>>>(w1, w1T, DIM_, HID_);
  cvt_transpose_kernel<<<dim3(DIM_/32, HID_/32), blk, 0, stream>>>(w2, w2T, HID_, DIM_);
  concat_bias_kernel<<<24, blk, 0, stream>>>(bq, bk, bv, cbias);
  // LN1
  ln_kernel<<<TOK_, blk, 0, stream>>>(x, nullptr, g1, b1, h_bf, 0);
  // fused QKV (256^2 kernel): [4096,2048] @ [6144,2048]^T -> qkv bf16
  gemm256<0><<<dim3(6144/256, TOK_/256, 1), gblk, 0, stream>>>(
      h_bf, wqkvT, qkv, cbias, nullptr, TOK_, 6144, DIM_, DIM_, DIM_, 6144, 0, 0, 0);
  // scores = q @ k^T (batched, 128x256 kernel)
  gemm8p<1><<<dim3(SEQ_/256, SEQ_/128, BATCH_), gblk, 0, stream>>>(
      qkv, qkv + DIM_, scores, nullptr, nullptr, SEQ_, SEQ_, DIM_, 6144, 6144, SEQ_,
      (long long)SEQ_ * 6144, (long long)SEQ_ * 6144, (long long)SEQ_ * SEQ_);
  // softmax -> bf16 probs
  softmax_kernel<<<BATCH_ * SEQ_, blk, 0, stream>>>(scores, mask, attn);
  // V transpose: (B,S,D) strided in qkv -> vT (B,D,S)
  transpose_bf16_kernel<<<dim3(DIM_/32, SEQ_/32, BATCH_), blk, 0, stream>>>(
      qkv + 2*DIM_, vT, 6144, SEQ_, (long long)SEQ_ * 6144, (long long)DIM_ * SEQ_);
  // attn_out = probs @ V (128x256 kernel)
  gemm8p<1><<<dim3(DIM_/256, SEQ_/128, BATCH_), gblk, 0, stream>>>(
      attn, vT, attno, nullptr, nullptr, SEQ_, DIM_, SEQ_, SEQ_, SEQ_, DIM_,
      (long long)SEQ_ * SEQ_, (long long)DIM_ * SEQ_, (long long)SEQ_ * DIM_);
  // LN2 over x + attn_out
  ln_kernel<<<TOK_, blk, 0, stream>>>(x, attno, g2, b2, h2, 1);
  // FFN1 (256^2 kernel): gelu(h2 @ w1 + b1) -> bf16
  gemm256<2><<<dim3(HID_/256, TOK_/256, 1), gblk, 0, stream>>>(
      h2, w1T, ffn1, bw1, nullptr, TOK_, HID_, DIM_, DIM_, DIM_, HID_, 0, 0, 0);
  // FFN2 (128x256 kernel): x + (ffn1 @ w2 + b2) -> fp32 d_out
  gemm8p<3><<<dim3(DIM_/256, TOK_/128, 1), gblk, 0, stream>>>(
      ffn1, w2T, out, bw2, x, TOK_, DIM_, HID_, HID_, HID_, DIM_, 0, 0, 0);
}

// Round 5
// 626.219 us; speedup vs baseline: 1.0922x; 1.0922x over previous
//
#include <hip/hip_runtime.h>
#include <math.h>

#define DIM_ 2048
#define HID_ 8192
#define SEQ_ 2048
#define BATCH_ 2
#define TOK_ (BATCH_*SEQ_)

typedef __attribute__((ext_vector_type(4))) float f32x4;
typedef __attribute__((ext_vector_type(8))) __bf16 bf16x8;
typedef __attribute__((ext_vector_type(4))) unsigned int u32x4;
typedef __attribute__((ext_vector_type(4))) short s16x4;
typedef __attribute__((ext_vector_type(8))) short s16x8;
typedef __attribute__((address_space(3))) short* lds_sp;

__device__ __forceinline__ short f2bf(float f) {
  union { float f; unsigned u; } v; v.f = f;
  unsigned r = v.u + 0x7FFFu + ((v.u >> 16) & 1u);
  return (short)(r >> 16);
}
__device__ __forceinline__ float bf2f(short s) {
  union { unsigned u; float f; } v; v.u = ((unsigned)(unsigned short)s) << 16;
  return v.f;
}

__device__ __forceinline__ f32x4 mfma16(u32x4 a, u32x4 b, f32x4 c) {
  return __builtin_amdgcn_mfma_f32_16x16x32_bf16(
      __builtin_bit_cast(bf16x8, a), __builtin_bit_cast(bf16x8, b), c, 0, 0, 0);
}

#define DSR(dst, addr) asm volatile("ds_read_b128 %0, %1" : "=v"(dst) : "v"(addr))
#define BARv()  __builtin_amdgcn_s_barrier()
#define LGKM0() do { asm volatile("s_waitcnt lgkmcnt(0)" ::: "memory"); \
                     __builtin_amdgcn_sched_barrier(0); } while(0)
#define LGKM8() asm volatile("s_waitcnt lgkmcnt(8)" ::: "memory")
#define VM6()   asm volatile("s_waitcnt vmcnt(6)" ::: "memory")
#define VM3()   asm volatile("s_waitcnt vmcnt(3)" ::: "memory")
#define PRIO1() __builtin_amdgcn_s_setprio(1)
#define PRIO0() __builtin_amdgcn_s_setprio(0)

// XCD-chunk + 4-column-group tile mapping (bijective; needs nwg%8==0, gx%4==0)
#define TILE_MAP(BM, BN) \
  const int nwg  = gridDim.x * gridDim.y; \
  const int orig = blockIdx.y * gridDim.x + blockIdx.x; \
  const int wgid = (orig & 7) * (nwg >> 3) + (orig >> 3); \
  const int gy4  = (int)gridDim.y << 2; \
  const int rem  = wgid % gy4; \
  const int tn   = ((wgid / gy4) * 4 + (rem & 3)) * (BN); \
  const int tm   = (rem >> 2) * (BM);

// shared epilogue
// EPI: 0 bias->bf16 | 1 raw f32 | 2 bias+GELU->bf16 | 3 bias+aux->f32
//      4 scale+mask->bf16 (aux = mask, per-batch rows)
template<int EPI>
__device__ __forceinline__ void epi_store(void* Cv, const float* bias, const float* aux,
                                          int z, long long sC, int ldc, int N,
                                          int row, int col, float v)
{
  if (EPI == 1) {
    ((float*)Cv + (long long)z * sC)[(long long)row * ldc + col] = v;
  } else if (EPI == 0) {
    v += bias[col];
    ((short*)Cv + (long long)z * sC)[(long long)row * ldc + col] = f2bf(v);
  } else if (EPI == 2) {
    v += bias[col];
    v = 0.5f * v * (1.0f + erff(v * 0.70710678118654752f));
    ((short*)Cv + (long long)z * sC)[(long long)row * ldc + col] = f2bf(v);
  } else if (EPI == 3) {
    v += bias[col] + aux[(long long)row * ldc + col];
    ((float*)Cv + (long long)z * sC)[(long long)row * ldc + col] = v;
  } else { // 4: scores: v*scale + mask[row][col] -> bf16
    v = v * 0.022097086912079608f + aux[(long long)row * ldc + col];
    ((short*)Cv + (long long)z * sC)[(long long)row * ldc + col] = f2bf(v);
  }
}

// ---------------------------------------------------------------------------
// gemm8p: 128x256 tile, BK=64, 3-slot rotation, 144KB LDS (1 wg/CU).
// Round-3 verified. Used for QKV, QK^T, PV.
// ---------------------------------------------------------------------------
#define RD_A(mlo, slot) do { \
  const unsigned ab_ = aBase8 + (unsigned)(slot)*16384u + (mlo)*2048u; \
  DSR(af[0][0], ab_ + offk0);         DSR(af[0][1], ab_ + offk1); \
  DSR(af[1][0], ab_ + 2048u + offk0); DSR(af[1][1], ab_ + 2048u + offk1); \
} while(0)

#define RD_B(slot) do { \
  const unsigned bb_ = bBase8 + (unsigned)(slot)*32768u; \
  DSR(bfr[0][0], bb_ + offk0);         DSR(bfr[0][1], bb_ + offk1); \
  DSR(bfr[1][0], bb_ + 2048u + offk0); DSR(bfr[1][1], bb_ + 2048u + offk1); \
  DSR(bfr[2][0], bb_ + 4096u + offk0); DSR(bfr[2][1], bb_ + 4096u + offk1); \
  DSR(bfr[3][0], bb_ + 6144u + offk0); DSR(bfr[3][1], bb_ + 6144u + offk1); \
} while(0)

#define MM(mlo) do { \
  _Pragma("unroll") \
  for (int n_ = 0; n_ < 4; ++n_) { \
    acc[(mlo)][n_]   = mfma16(af[0][0], bfr[n_][0], acc[(mlo)][n_]); \
    acc[(mlo)][n_]   = mfma16(af[0][1], bfr[n_][1], acc[(mlo)][n_]); \
    acc[(mlo)+1][n_] = mfma16(af[1][0], bfr[n_][0], acc[(mlo)+1][n_]); \
    acc[(mlo)+1][n_] = mfma16(af[1][1], bfr[n_][1], acc[(mlo)+1][n_]); \
  } \
} while(0)

template<int EPI>
__global__ __launch_bounds__(512, 2)
void gemm8p(const short* __restrict__ A, const short* __restrict__ B,
            void* __restrict__ Cv, const float* __restrict__ bias,
            const float* __restrict__ aux,
            int M, int N, int K, int lda, int ldb, int ldc,
            long long sA, long long sB, long long sC)
{
  __shared__ __align__(16) short As[3*128*64];
  __shared__ __align__(16) short Bs[3*256*64];
  const int lane = threadIdx.x & 63;
  const int wave = threadIdx.x >> 6;
  const int wr = wave >> 2, wc = wave & 3;
  TILE_MAP(128, 256)
  const int z  = blockIdx.z;
  A += (long long)z * sA;
  B += (long long)z * sB;

  const int NT = K >> 6;

  const int lr    = lane >> 3;
  const int lrow  = wave * 8 + lr;
  const int lslot = ((lane & 7) ^ lr) << 3;
  const short* pA = A + (long long)(tm + lrow) * lda + lslot;
  const short* pB = B + (long long)(tn + lrow) * ldb + lslot;
  const long long lda64 = 64LL * lda;
  const long long ldb64 = 64LL * ldb;

  auto stageA = [&](int t, int slot) {
    const long long ko = (long long)t << 6;
    const int db = slot * 8192 + wave * 512;
    __builtin_amdgcn_global_load_lds(
        (const __attribute__((address_space(1))) void*)(pA + ko),
        (__attribute__((address_space(3))) void*)(As + db), 16, 0, 0);
    __builtin_amdgcn_global_load_lds(
        (const __attribute__((address_space(1))) void*)(pA + lda64 + ko),
        (__attribute__((address_space(3))) void*)(As + db + 4096), 16, 0, 0);
  };
  auto stageB = [&](int t, int slot) {
    const long long ko = (long long)t << 6;
    const int db = slot * 16384 + wave * 512;
    __builtin_amdgcn_global_load_lds(
        (const __attribute__((address_space(1))) void*)(pB + ko),
        (__attribute__((address_space(3))) void*)(Bs + db), 16, 0, 0);
    __builtin_amdgcn_global_load_lds(
        (const __attribute__((address_space(1))) void*)(pB + ldb64 + ko),
        (__attribute__((address_space(3))) void*)(Bs + db + 4096), 16, 0, 0);
    __builtin_amdgcn_global_load_lds(
        (const __attribute__((address_space(1))) void*)(pB + 2*ldb64 + ko),
        (__attribute__((address_space(3))) void*)(Bs + db + 8192), 16, 0, 0);
    __builtin_amdgcn_global_load_lds(
        (const __attribute__((address_space(1))) void*)(pB + 3*ldb64 + ko),
        (__attribute__((address_space(3))) void*)(Bs + db + 12288), 16, 0, 0);
  };

  const unsigned asB = (unsigned)(unsigned long long)(lds_sp)As;
  const unsigned bsB = (unsigned)(unsigned long long)(lds_sp)Bs;
  const int l15 = lane & 15, l4 = lane >> 4;
  const unsigned offk0 = (unsigned)(( l4      ^ (lane & 7)) << 4);
  const unsigned offk1 = (unsigned)(((l4 + 4) ^ (lane & 7)) << 4);
  const unsigned aBase8 = asB + (unsigned)((wr * 64 + l15) * 128);
  const unsigned bBase8 = bsB + (unsigned)((wc * 64 + l15) * 128);

  f32x4 acc[4][4] = {};
  u32x4 af[2][2], bfr[4][2];

  stageB(0, 0); stageA(0, 0);
  stageB(1 < NT ? 1 : 0, 1); stageA(1 < NT ? 1 : 0, 1);
  VM6();
  BARv();

  int rd = 0;
  #pragma unroll 1
  for (int t = 0; t < NT; ++t) {
    const int st = rd + 2 >= 3 ? rd - 1 : rd + 2;
    const int tc = t + 2 < NT ? t + 2 : NT - 1;
    RD_A(0, rd); RD_B(rd);
    stageB(tc, st);
    LGKM8();
    BARv(); LGKM0();
    PRIO1(); MM(0); PRIO0();
    BARv();
    RD_A(2, rd);
    stageA(tc, st);
    VM6();
    BARv(); LGKM0();
    PRIO1(); MM(2); PRIO0();
    BARv();
    rd = rd + 1 >= 3 ? 0 : rd + 1;
  }

  const int row0 = tm + wr * 64 + l4 * 4;
  const int col0 = tn + wc * 64 + l15;
  #pragma unroll
  for (int mi = 0; mi < 4; ++mi)
    #pragma unroll
    for (int j = 0; j < 4; ++j)
      #pragma unroll
      for (int ni = 0; ni < 4; ++ni)
        epi_store<EPI>(Cv, bias, aux, z, sC, ldc, N,
                       row0 + mi * 16 + j, col0 + ni * 16, acc[mi][ni][j]);
}

// ---------------------------------------------------------------------------
// gemm_hi: 128x256 tile, BK=32, 3-slot rotation, 72KB LDS -> 2 wg/CU.
// Single phase per K-step: {8 ds_read || 3 gload_lds} bar lgkm0 16MFMA vm3 bar.
// Cross-block overlap (m114/m97 mechanism) hides the barrier drains.
// ---------------------------------------------------------------------------
#define HRD(slot) do { \
  const unsigned a_ = aBaseH + (unsigned)(slot)*8192u; \
  const unsigned b_ = bBaseH + (unsigned)(slot)*16384u; \
  DSR(af[0], a_ + offk);          DSR(af[1], a_ + 1024u + offk); \
  DSR(af[2], a_ + 2048u + offk);  DSR(af[3], a_ + 3072u + offk); \
  DSR(bf[0], b_ + offk);          DSR(bf[1], b_ + 1024u + offk); \
  DSR(bf[2], b_ + 2048u + offk);  DSR(bf[3], b_ + 3072u + offk); \
} while(0)

#define HMM() do { \
  _Pragma("unroll") \
  for (int mi = 0; mi < 4; ++mi) \
    _Pragma("unroll") \
    for (int ni = 0; ni < 4; ++ni) \
      acc[mi][ni] = mfma16(af[mi], bf[ni], acc[mi][ni]); \
} while(0)

template<int EPI>
__global__ __launch_bounds__(512, 4)
void gemm_hi(const short* __restrict__ A, const short* __restrict__ B,
             void* __restrict__ Cv, const float* __restrict__ bias,
             const float* __restrict__ aux,
             int M, int N, int K, int lda, int ldb, int ldc,
             long long sA, long long sB, long long sC)
{
  __shared__ __align__(16) short As[3*128*32];   // 24 KB
  __shared__ __align__(16) short Bs[3*256*32];   // 48 KB
  const int lane = threadIdx.x & 63;
  const int wave = threadIdx.x >> 6;
  const int wr = wave >> 2, wc = wave & 3;
  TILE_MAP(128, 256)
  const int z = blockIdx.z;
  A += (long long)z * sA;
  B += (long long)z * sB;

  const int NT = K >> 5;   // 32-wide K-steps

  // staging: A = 1 call (8KB), B = 2 calls. lane covers row = wave*16 + (lane>>2),
  // 16B slot (lane&3); source pre-swizzled: logical slot = (lane&3) ^ (row&3).
  const int rr   = wave * 16 + (lane >> 2);
  const int soff = (((lane & 3) ^ ((lane >> 2) & 3)) << 3);  // elements
  const short* pA = A + (long long)(tm + rr) * lda + soff;
  const short* pB = B + (long long)(tn + rr) * ldb + soff;
  const long long ldb128 = 128LL * ldb;

  auto stage = [&](int t, int slot) {
    const long long ko = (long long)t << 5;
    __builtin_amdgcn_global_load_lds(
        (const __attribute__((address_space(1))) void*)(pA + ko),
        (__attribute__((address_space(3))) void*)(As + slot * 4096 + wave * 512), 16, 0, 0);
    __builtin_amdgcn_global_load_lds(
        (const __attribute__((address_space(1))) void*)(pB + ko),
        (__attribute__((address_space(3))) void*)(Bs + slot * 8192 + wave * 512), 16, 0, 0);
    __builtin_amdgcn_global_load_lds(
        (const __attribute__((address_space(1))) void*)(pB + ldb128 + ko),
        (__attribute__((address_space(3))) void*)(Bs + slot * 8192 + 4096 + wave * 512), 16, 0, 0);
  };

  // reads: row = (wr|wc)*64 + l15 + 16*i ; phys slot = l4 ^ (row&3) = l4 ^ (l15&3)
  const unsigned asB = (unsigned)(unsigned long long)(lds_sp)As;
  const unsigned bsB = (unsigned)(unsigned long long)(lds_sp)Bs;
  const int l15 = lane & 15, l4 = lane >> 4;
  const unsigned offk  = (unsigned)((l4 ^ (l15 & 3)) << 4);
  const unsigned aBaseH = asB + (unsigned)(wr * 4096 + l15 * 64);
  const unsigned bBaseH = bsB + (unsigned)(wc * 4096 + l15 * 64);

  f32x4 acc[4][4] = {};
  u32x4 af[4], bf[4];

  stage(0, 0);
  stage(1 < NT ? 1 : 0, 1);
  VM3();
  BARv();

  int rd = 0;
  #pragma unroll 1
  for (int t = 0; t < NT; ++t) {
    const int st = rd + 2 >= 3 ? rd - 1 : rd + 2;
    const int tc = t + 2 < NT ? t + 2 : NT - 1;
    HRD(rd);
    stage(tc, st);
    BARv(); LGKM0();
    PRIO1(); HMM(); PRIO0();
    VM3();
    BARv();
    rd = rd + 1 >= 3 ? 0 : rd + 1;
  }

  const int row0 = tm + wr * 64 + l4 * 4;
  const int col0 = tn + wc * 64 + l15;
  #pragma unroll
  for (int mi = 0; mi < 4; ++mi)
    #pragma unroll
    for (int j = 0; j < 4; ++j)
      #pragma unroll
      for (int ni = 0; ni < 4; ++ni)
        epi_store<EPI>(Cv, bias, aux, z, sC, ldc, N,
                       row0 + mi * 16 + j, col0 + ni * 16, acc[mi][ni][j]);
}

// ---------------------------------------------------------------------------
// LayerNorm: out_bf16[row] = LN(x[row] (+ res[row])) * g + b
// ---------------------------------------------------------------------------
__global__ __launch_bounds__(256)
void ln_kernel(const float* __restrict__ x, const float* __restrict__ res,
               const float* __restrict__ g, const float* __restrict__ b,
               short* __restrict__ out, int hasres)
{
  const int row = blockIdx.x;
  const int tid = threadIdx.x;
  const float4* X = (const float4*)x + (long long)row * 512;
  float4 v0 = X[tid], v1 = X[tid + 256];
  if (hasres) {
    const float4* R = (const float4*)res + (long long)row * 512;
    float4 r0 = R[tid], r1 = R[tid + 256];
    v0.x += r0.x; v0.y += r0.y; v0.z += r0.z; v0.w += r0.w;
    v1.x += r1.x; v1.y += r1.y; v1.z += r1.z; v1.w += r1.w;
  }
  float s1 = v0.x + v0.y + v0.z + v0.w + v1.x + v1.y + v1.z + v1.w;
  float s2 = v0.x*v0.x + v0.y*v0.y + v0.z*v0.z + v0.w*v0.w
           + v1.x*v1.x + v1.y*v1.y + v1.z*v1.z + v1.w*v1.w;
  #pragma unroll
  for (int o = 32; o > 0; o >>= 1) { s1 += __shfl_xor(s1, o); s2 += __shfl_xor(s2, o); }
  __shared__ float red[8];
  if ((tid & 63) == 0) { red[tid >> 6] = s1; red[4 + (tid >> 6)] = s2; }
  __syncthreads();
  s1 = red[0] + red[1] + red[2] + red[3];
  s2 = red[4] + red[5] + red[6] + red[7];
  const float mean = s1 * (1.0f / 2048.0f);
  const float var  = s2 * (1.0f / 2048.0f) - mean * mean;
  const float rstd = rsqrtf(var + 1e-5f);
  const float4* G  = (const float4*)g;
  const float4* Bb = (const float4*)b;
  float4 g0 = G[tid], g1 = G[tid + 256], b0 = Bb[tid], b1 = Bb[tid + 256];
  s16x4 o0, o1;
  o0[0] = f2bf((v0.x - mean) * rstd * g0.x + b0.x);
  o0[1] = f2bf((v0.y - mean) * rstd * g0.y + b0.y);
  o0[2] = f2bf((v0.z - mean) * rstd * g0.z + b0.z);
  o0[3] = f2bf((v0.w - mean) * rstd * g0.w + b0.w);
  o1[0] = f2bf((v1.x - mean) * rstd * g1.x + b1.x);
  o1[1] = f2bf((v1.y - mean) * rstd * g1.y + b1.y);
  o1[2] = f2bf((v1.z - mean) * rstd * g1.z + b1.z);
  o1[3] = f2bf((v1.w - mean) * rstd * g1.w + b1.w);
  *(s16x4*)&out[(long long)row * 2048 + tid * 4]        = o0;
  *(s16x4*)&out[(long long)row * 2048 + 1024 + tid * 4] = o1;
}

// ---------------------------------------------------------------------------
// In-place softmax over bf16 rows (scale+mask already applied by QK^T epilogue)
// ---------------------------------------------------------------------------
__global__ __launch_bounds__(256)
void softmax_bf16_kernel(short* __restrict__ probs)
{
  const long long row = blockIdx.x;
  const int tid = threadIdx.x;
  short* P = probs + row * 2048 + tid * 8;
  s16x8 in = *(const s16x8*)P;
  float a[8];
  #pragma unroll
  for (int i = 0; i < 8; ++i) a[i] = bf2f(in[i]);
  float mx = a[0];
  #pragma unroll
  for (int i = 1; i < 8; ++i) mx = fmaxf(mx, a[i]);
  #pragma unroll
  for (int o = 32; o > 0; o >>= 1) mx = fmaxf(mx, __shfl_xor(mx, o));
  __shared__ float red[8];
  if ((tid & 63) == 0) red[tid >> 6] = mx;
  __syncthreads();
  mx = fmaxf(fmaxf(red[0], red[1]), fmaxf(red[2], red[3]));
  float e[8], sum = 0.f;
  #pragma unroll
  for (int i = 0; i < 8; ++i) { e[i] = __expf(a[i] - mx); sum += e[i]; }
  #pragma unroll
  for (int o = 32; o > 0; o >>= 1) sum += __shfl_xor(sum, o);
  if ((tid & 63) == 0) red[4 + (tid >> 6)] = sum;
  __syncthreads();
  sum = red[4] + red[5] + red[6] + red[7];
  const float inv = 1.0f / sum;
  s16x8 o;
  #pragma unroll
  for (int i = 0; i < 8; ++i) o[i] = f2bf(e[i] * inv);
  *(s16x8*)P = o;
}

// ---------------------------------------------------------------------------
// fp32 (R,C) -> bf16 (C,R) transpose-convert, 64x64 tiles, float4 loads
// ---------------------------------------------------------------------------
__global__ __launch_bounds__(256)
void cvt_transpose64(const float* __restrict__ in, short* __restrict__ out,
                     int R, int C)
{
  __shared__ float t[64][69];
  const int r0 = blockIdx.y << 6, c0 = blockIdx.x << 6;
  const int tx = threadIdx.x & 15, ty = threadIdx.x >> 4;
  #pragma unroll
  for (int p = 0; p < 4; ++p) {
    const int r = ty + p * 16;
    float4 v = *(const float4*)&in[(long long)(r0 + r) * C + c0 + tx * 4];
    t[r][tx*4+0] = v.x; t[r][tx*4+1] = v.y; t[r][tx*4+2] = v.z; t[r][tx*4+3] = v.w;
  }
  __syncthreads();
  #pragma unroll
  for (int p = 0; p < 4; ++p) {
    const int oc = ty + p * 16;
    s16x4 o;
    o[0] = f2bf(t[tx*4+0][oc]); o[1] = f2bf(t[tx*4+1][oc]);
    o[2] = f2bf(t[tx*4+2][oc]); o[3] = f2bf(t[tx*4+3][oc]);
    *(s16x4*)&out[(long long)(c0 + oc) * R + r0 + tx * 4] = o;
  }
}

// bf16 strided (z,R,C) -> (z,C,R) transpose (V)
__global__ __launch_bounds__(256)
void transpose_bf16_kernel(const short* __restrict__ in, short* __restrict__ out,
                           int ldin, int ldout, long long sin_, long long sout_)
{
  __shared__ short t[32][33];
  in  += (long long)blockIdx.z * sin_;
  out += (long long)blockIdx.z * sout_;
  const int tx = threadIdx.x & 31, ty = threadIdx.x >> 5;
  const int r0 = blockIdx.y << 5, c0 = blockIdx.x << 5;
  #pragma unroll
  for (int i = 0; i < 32; i += 8)
    t[ty + i][tx] = in[(long long)(r0 + ty + i) * ldin + c0 + tx];
  __syncthreads();
  #pragma unroll
  for (int i = 0; i < 32; i += 8)
    out[(long long)(c0 + ty + i) * ldout + r0 + tx] = t[tx][ty + i];
}

__global__ __launch_bounds__(256)
void concat_bias_kernel(const float* a, const float* b, const float* c, float* o)
{
  const int i = blockIdx.x * 256 + threadIdx.x;   // 6144
  o[i] = i < 2048 ? a[i] : (i < 4096 ? b[i - 2048] : c[i - 4096]);
}

// ---------------------------------------------------------------------------
extern "C" void kernel_launch(void* const* d_in, const int* in_sizes, int n_in,
                              void* d_out, int out_size, void* d_ws, size_t ws_size,
                              hipStream_t stream)
{
  const float* x    = (const float*)d_in[0];
  const float* mask = (const float*)d_in[1];
  const float* wq   = (const float*)d_in[4];
  const float* bq   = (const float*)d_in[5];
  const float* wk   = (const float*)d_in[6];
  const float* bk   = (const float*)d_in[7];
  const float* wv   = (const float*)d_in[8];
  const float* bv   = (const float*)d_in[9];
  const float* g1   = (const float*)d_in[10];
  const float* b1   = (const float*)d_in[11];
  const float* g2   = (const float*)d_in[12];
  const float* b2   = (const float*)d_in[13];
  const float* w1   = (const float*)d_in[14];
  const float* bw1  = (const float*)d_in[15];
  const float* w2   = (const float*)d_in[16];
  const float* bw2  = (const float*)d_in[17];
  float* out = (float*)d_out;

  char* p = (char*)d_ws;
  auto take = [&](size_t bytes) { char* r = p; p += (bytes + 255) & ~(size_t)255; return r; };
  short* wqkvT = (short*)take((size_t)3 * DIM_ * DIM_ * 2);  // [6144][2048] bf16
  short* w1T   = (short*)take((size_t)DIM_ * HID_ * 2);      // [8192][2048]
  short* w2T   = (short*)take((size_t)HID_ * DIM_ * 2);      // [2048][8192]
  short* h_bf  = (short*)take((size_t)TOK_ * DIM_ * 2);      // reused as h2
  short* qkv   = (short*)take((size_t)TOK_ * 3 * DIM_ * 2);  // [4096][6144]
  short* vT    = (short*)take((size_t)BATCH_ * DIM_ * SEQ_ * 2);
  float* attno = (float*)take((size_t)TOK_ * DIM_ * 4);      // 32MB
  short* attn  = (short*)take((size_t)BATCH_ * SEQ_ * SEQ_ * 2);
  float* cbias = (float*)take((size_t)3 * DIM_ * 4);
  short* ffn1  = qkv;          // alias over qkv+vT (dead after PV)
  short* h2    = h_bf;         // alias (h dead after QKV)

  const dim3 blk(256), gblk(512);
  // weight convert+transpose (vectorized 64x64)
  cvt_transpose64<<<dim3(DIM_/64, DIM_/64), blk, 0, stream>>>(wq, wqkvT, DIM_, DIM_);
  cvt_transpose64<<<dim3(DIM_/64, DIM_/64), blk, 0, stream>>>(wk, wqkvT + (size_t)DIM_*DIM_, DIM_, DIM_);
  cvt_transpose64<<<dim3(DIM_/64, DIM_/64), blk, 0, stream>>>(wv, wqkvT + (size_t)2*DIM_*DIM_, DIM_, DIM_);
  cvt_transpose64<<<dim3(HID_/64, DIM_/64), blk, 0, stream>>>(w1, w1T, DIM_, HID_);
  cvt_transpose64<<<dim3(DIM_/64, HID_/64), blk, 0, stream>>>(w2, w2T, HID_, DIM_);
  concat_bias_kernel<<<24, blk, 0, stream>>>(bq, bk, bv, cbias);
  // LN1
  ln_kernel<<<TOK_, blk, 0, stream>>>(x, nullptr, g1, b1, h_bf, 0);
  // fused QKV: [4096,2048] @ [6144,2048]^T -> qkv bf16 [4096][6144]
  gemm8p<0><<<dim3(6144/256, TOK_/128, 1), gblk, 0, stream>>>(
      h_bf, wqkvT, qkv, cbias, nullptr, TOK_, 6144, DIM_, DIM_, DIM_, 6144, 0, 0, 0);
  // scores (scale+mask fused) -> bf16 attn
  gemm8p<4><<<dim3(SEQ_/256, SEQ_/128, BATCH_), gblk, 0, stream>>>(
      qkv, qkv + DIM_, attn, nullptr, mask, SEQ_, SEQ_, DIM_, 6144, 6144, SEQ_,
      (long long)SEQ_ * 6144, (long long)SEQ_ * 6144, (long long)SEQ_ * SEQ_);
  // in-place softmax on bf16 rows
  softmax_bf16_kernel<<<BATCH_ * SEQ_, blk, 0, stream>>>(attn);
  // V transpose: (B,S,D) strided in qkv -> vT (B,D,S)
  transpose_bf16_kernel<<<dim3(DIM_/32, SEQ_/32, BATCH_), blk, 0, stream>>>(
      qkv + 2*DIM_, vT, 6144, SEQ_, (long long)SEQ_ * 6144, (long long)DIM_ * SEQ_);
  // attn_out = probs @ V
  gemm8p<1><<<dim3(DIM_/256, SEQ_/128, BATCH_), gblk, 0, stream>>>(
      attn, vT, attno, nullptr, nullptr, SEQ_, DIM_, SEQ_, SEQ_, SEQ_, DIM_,
      (long long)SEQ_ * SEQ_, (long long)DIM_ * SEQ_, (long long)SEQ_ * DIM_);
  // LN2 over x + attn_out
  ln_kernel<<<TOK_, blk, 0, stream>>>(x, attno, g2, b2, h2, 1);
  // FFN1 (gemm_hi, 2 wg/CU): gelu(h2 @ w1 + b1) -> bf16
  gemm_hi<2><<<dim3(HID_/256, TOK_/128, 1), gblk, 0, stream>>>(
      h2, w1T, ffn1, bw1, nullptr, TOK_, HID_, DIM_, DIM_, DIM_, HID_, 0, 0, 0);
  // FFN2 (gemm_hi): x + (ffn1 @ w2 + b2) -> fp32 d_out
  gemm_hi<3><<<dim3(DIM_/256, TOK_/128, 1), gblk, 0, stream>>>(
      ffn1, w2T, out, bw2, x, TOK_, DIM_, HID_, HID_, HID_, DIM_, 0, 0, 0);
}